// Round 2
// baseline (1432.469 us; speedup 1.0000x reference)
//
#include <hip/hip_runtime.h>

// Fused attention block (b=2, n=2048, dim=256, heads=8, inner=16384, d_head=2048)
// Pipeline: cast W->bf16 (SCALE folded into Wq) ; LN->xn bf16 ;
//   Q = xn@Wq^T ; K = xn@Wk^T ; S = Q@K^T ; softmax ; Vt = Wv@xn^T ; O = P@Vt^T ;
//   out = O@Wo^T (split-K, fp32 atomic).
// All GEMMs are B^T-form (both operands k-contiguous), m97 recipe: 128x128 tile,
// BK=32, mfma_f32_16x16x32_bf16, global_load_lds width=16, 2-barrier K-loop.
// Host tiers on ws_size: A = fully batched (438 MiB), B = per-head loop (103 MiB),
// C = per-(batch,head) loop (66 MiB). Same kernels, different pointers/grids.

typedef unsigned short u16;
typedef unsigned int u32;
typedef __bf16 bf16x8 __attribute__((ext_vector_type(8)));
typedef float f32x4 __attribute__((ext_vector_type(4)));

__device__ __forceinline__ u16 f2bf(float f) {
    u32 u = __builtin_bit_cast(u32, f);
    u += 0x7fffu + ((u >> 16) & 1u);   // RNE; inputs finite
    return (u16)(u >> 16);
}
__device__ __forceinline__ float bf2f(u16 h) {
    u32 u = ((u32)h) << 16;
    return __builtin_bit_cast(float, u);
}

#define GLDS16(G, L)                                                                  \
    __builtin_amdgcn_global_load_lds((const __attribute__((address_space(1))) u32*)(G), \
                                     (__attribute__((address_space(3))) u32*)(L), 16, 0, 0)

// ---------------------------------------------------------------------------
// B^T GEMM: C[m,n] (+)= sum_k A[m,k] * B[n,k].  M,N multiples of 128, K of 32.
// Batch/split-K via blockIdx.z: zh = z%H, zb = z/H; offsets via strides.
// ---------------------------------------------------------------------------
template <typename OutT, bool ATOMIC>
__global__ void __launch_bounds__(256, 2) gemm_bt(
    const u16* __restrict__ A, const u16* __restrict__ B, OutT* __restrict__ C,
    int K, int lda, int ldb, int ldc,
    long sAh, long sAb, long sBh, long sBb, long sCh, long sCb, int H)
{
    __shared__ u16 ldsA[128 * 32];
    __shared__ u16 ldsB[128 * 32];

    const int z = blockIdx.z;
    const int zh = z % H, zb = z / H;
    A += (size_t)zh * sAh + (size_t)zb * sAb;
    B += (size_t)zh * sBh + (size_t)zb * sBb;
    C += (size_t)zh * sCh + (size_t)zb * sCb;

    const int bm = blockIdx.y * 128;
    const int bn = blockIdx.x * 128;
    const int t = threadIdx.x;
    const int w = t >> 6, l = t & 63;
    const int wm = w >> 1, wn = w & 1;          // 2x2 waves, each 64x64
    const int lr = l & 15, lk = l >> 4;         // frag row / k-chunk
    const int sw = lk ^ ((lr >> 1) & 3);        // XOR-swizzled slot (2-way LDS = free)

    // staging: 512 chunks of 16B per tile; thread t covers chunks t and 256+t.
    // LDS slot s of row m holds global k-chunk c = s ^ ((m>>1)&3).
    const int m0 = t >> 2, s0 = t & 3;
    const int c0 = s0 ^ ((m0 >> 1) & 3);
    const int m1 = 64 + m0;
    const int c1 = s0 ^ ((m1 >> 1) & 3);

    const u16* gA0 = A + (size_t)(bm + m0) * lda + c0 * 8;
    const u16* gA1 = A + (size_t)(bm + m1) * lda + c1 * 8;
    const u16* gB0 = B + (size_t)(bn + m0) * ldb + c0 * 8;
    const u16* gB1 = B + (size_t)(bn + m1) * ldb + c1 * 8;
    u16* lA0 = &ldsA[(t & ~63) * 8];            // wave-uniform base; HW adds lane*16B
    u16* lA1 = &ldsA[(256 + (t & ~63)) * 8];
    u16* lB0 = &ldsB[(t & ~63) * 8];
    u16* lB1 = &ldsB[(256 + (t & ~63)) * 8];

    f32x4 acc[4][4];
#pragma unroll
    for (int i = 0; i < 4; ++i)
#pragma unroll
        for (int j = 0; j < 4; ++j)
            acc[i][j] = f32x4{0.f, 0.f, 0.f, 0.f};

    const int nk = K >> 5;
    for (int kt = 0; kt < nk; ++kt) {
        __syncthreads();                         // protect LDS from prev iter's readers
        GLDS16(gA0, lA0); GLDS16(gA1, lA1);
        GLDS16(gB0, lB0); GLDS16(gB1, lB1);
        gA0 += 32; gA1 += 32; gB0 += 32; gB1 += 32;
        __syncthreads();                         // drains vmcnt -> tile staged

        bf16x8 av[4], bv[4];
#pragma unroll
        for (int i = 0; i < 4; ++i) {
            av[i] = *(const bf16x8*)&ldsA[(wm * 64 + i * 16 + lr) * 32 + sw * 8];
            bv[i] = *(const bf16x8*)&ldsB[(wn * 64 + i * 16 + lr) * 32 + sw * 8];
        }
#pragma unroll
        for (int i = 0; i < 4; ++i)
#pragma unroll
            for (int j = 0; j < 4; ++j)
                acc[i][j] = __builtin_amdgcn_mfma_f32_16x16x32_bf16(av[i], bv[j], acc[i][j], 0, 0, 0);
    }

    // C/D layout (m89-verified): col = lane&15, row = (lane>>4)*4 + reg
#pragma unroll
    for (int i = 0; i < 4; ++i) {
        const int row0 = bm + wm * 64 + i * 16 + lk * 4;
#pragma unroll
        for (int j = 0; j < 4; ++j) {
            const int col = bn + wn * 64 + j * 16 + lr;
#pragma unroll
            for (int r = 0; r < 4; ++r) {
                const size_t idx = (size_t)(row0 + r) * ldc + col;
                const float v = acc[i][j][r];
                if constexpr (ATOMIC) {
                    atomicAdd(&C[idx], v);
                } else if constexpr (sizeof(OutT) == 2) {
                    C[idx] = (OutT)f2bf(v);
                } else {
                    C[idx] = (OutT)v;
                }
            }
        }
    }
}

// ---------------------------------------------------------------------------
// LayerNorm over dim=256, out = xn*(gamma+1) in bf16. One wave per row.
// ---------------------------------------------------------------------------
__global__ void __launch_bounds__(64) ln_kernel(const float* __restrict__ x,
                                                const float* __restrict__ g,
                                                u16* __restrict__ xn)
{
    const size_t row = blockIdx.x;
    const int l = threadIdx.x;
    const float4 v = ((const float4*)(x + row * 256))[l];
    float s = v.x + v.y + v.z + v.w;
    float q = v.x * v.x + v.y * v.y + v.z * v.z + v.w * v.w;
#pragma unroll
    for (int o = 32; o > 0; o >>= 1) {
        s += __shfl_xor(s, o, 64);
        q += __shfl_xor(q, o, 64);
    }
    const float mu = s * (1.0f / 256.0f);
    const float var = q * (1.0f / 256.0f) - mu * mu;
    const float rs = rsqrtf(var + 1e-5f);
    const float4 gg = ((const float4*)g)[l];
    ushort4 o4;
    o4.x = f2bf((v.x - mu) * rs * (gg.x + 1.0f));
    o4.y = f2bf((v.y - mu) * rs * (gg.y + 1.0f));
    o4.z = f2bf((v.z - mu) * rs * (gg.z + 1.0f));
    o4.w = f2bf((v.w - mu) * rs * (gg.w + 1.0f));
    ((ushort4*)(xn + row * 256))[l] = o4;
}

// fp32 -> bf16 cast with scale (SCALE=0.125 folded into Wq; pow2 => exact)
__global__ void __launch_bounds__(256) cast_bf16_kernel(const float* __restrict__ src,
                                                        u16* __restrict__ dst, float scale)
{
    const size_t i = (size_t)blockIdx.x * 256 + threadIdx.x;
    const float4 v = ((const float4*)src)[i];
    ushort4 o4;
    o4.x = f2bf(v.x * scale);
    o4.y = f2bf(v.y * scale);
    o4.z = f2bf(v.z * scale);
    o4.w = f2bf(v.w * scale);
    ((ushort4*)dst)[i] = o4;
}

// row softmax over 2048 bf16 elements, in-place. 256 threads, 8 elems each.
__global__ void __launch_bounds__(256) softmax_kernel(u16* __restrict__ S)
{
    const size_t row = blockIdx.x;
    uint4* p = (uint4*)(S + row * 2048);
    const int t = threadIdx.x;
    const int wv = t >> 6, ln = t & 63;
    const uint4 d = p[t];
    u32 us[4] = {d.x, d.y, d.z, d.w};
    float x[8];
#pragma unroll
    for (int i = 0; i < 4; ++i) {
        x[2 * i]     = bf2f((u16)(us[i] & 0xffffu));
        x[2 * i + 1] = __builtin_bit_cast(float, us[i] & 0xffff0000u);
    }
    float m = x[0];
#pragma unroll
    for (int i = 1; i < 8; ++i) m = fmaxf(m, x[i]);
#pragma unroll
    for (int o = 32; o > 0; o >>= 1) m = fmaxf(m, __shfl_xor(m, o, 64));
    __shared__ float redm[4], reds[4];
    if (ln == 0) redm[wv] = m;
    __syncthreads();
    m = fmaxf(fmaxf(redm[0], redm[1]), fmaxf(redm[2], redm[3]));
    float e[8];
    float s = 0.f;
#pragma unroll
    for (int i = 0; i < 8; ++i) { e[i] = __expf(x[i] - m); s += e[i]; }
#pragma unroll
    for (int o = 32; o > 0; o >>= 1) s += __shfl_xor(s, o, 64);
    if (ln == 0) reds[wv] = s;
    __syncthreads();
    s = reds[0] + reds[1] + reds[2] + reds[3];
    const float inv = 1.0f / s;
    uint4 o4;
    o4.x = (u32)f2bf(e[0] * inv) | ((u32)f2bf(e[1] * inv) << 16);
    o4.y = (u32)f2bf(e[2] * inv) | ((u32)f2bf(e[3] * inv) << 16);
    o4.z = (u32)f2bf(e[4] * inv) | ((u32)f2bf(e[5] * inv) << 16);
    o4.w = (u32)f2bf(e[6] * inv) | ((u32)f2bf(e[7] * inv) << 16);
    p[t] = o4;
}

extern "C" void kernel_launch(void* const* d_in, const int* in_sizes, int n_in,
                              void* d_out, int out_size, void* d_ws, size_t ws_size,
                              hipStream_t stream)
{
    (void)in_sizes; (void)n_in;
    const float* x     = (const float*)d_in[0];
    const float* gamma = (const float*)d_in[1];
    const float* Wq    = (const float*)d_in[2];
    const float* Wk    = (const float*)d_in[3];
    const float* Wv    = (const float*)d_in[4];
    const float* Wo    = (const float*)d_in[5];
    float* out = (float*)d_out;

    char* ws = (char*)d_ws;
    const size_t WB   = 8388608;     // 16384*256*2  (one bf16 weight)
    const size_t XNB  = 2097152;     // 4096*256*2
    const size_t BIG  = 134217728;   // 16*2048*2048*2
    const size_t MID  = 16777216;    // 4096*2048*2
    const size_t SMALL= 8388608;     // 2048*2048*2
    const size_t BASE = 4 * WB + XNB;

    u16* wq = (u16*)(ws);
    u16* wk = (u16*)(ws + WB);
    u16* wv = (u16*)(ws + 2 * WB);
    u16* wo = (u16*)(ws + 3 * WB);
    u16* xn = (u16*)(ws + 4 * WB);
    char* buf = ws + BASE;

    hipMemsetAsync(d_out, 0, (size_t)out_size * sizeof(float), stream);  // split-K accumulator

    cast_bf16_kernel<<<4096, 256, 0, stream>>>(Wq, wq, 0.125f);  // SCALE folded into Wq
    cast_bf16_kernel<<<4096, 256, 0, stream>>>(Wk, wk, 1.0f);
    cast_bf16_kernel<<<4096, 256, 0, stream>>>(Wv, wv, 1.0f);
    cast_bf16_kernel<<<4096, 256, 0, stream>>>(Wo, wo, 1.0f);

    ln_kernel<<<4096, 64, 0, stream>>>(x, gamma, xn);

    if (ws_size >= BASE + 3 * BIG) {
        // ---- Tier A: fully batched (438 MiB) ----
        u16* bufQ = (u16*)(buf);             // Q, then Vt
        u16* bufK = (u16*)(buf + BIG);       // K, then O
        u16* bufS = (u16*)(buf + 2 * BIG);   // S -> P

        gemm_bt<u16, false><<<dim3(128, 32, 1), 256, 0, stream>>>(
            xn, wq, bufQ, 256, 256, 256, 16384, 0, 0, 0, 0, 0, 0, 1);
        gemm_bt<u16, false><<<dim3(128, 32, 1), 256, 0, stream>>>(
            xn, wk, bufK, 256, 256, 256, 16384, 0, 0, 0, 0, 0, 0, 1);
        // S[b,h,i,j] = sum_d Q[b,i,h*2048+d] * K[b,j,h*2048+d]
        gemm_bt<u16, false><<<dim3(16, 16, 16), 256, 0, stream>>>(
            bufQ, bufK, bufS, 2048, 16384, 16384, 2048,
            2048, 2048L * 16384, 2048, 2048L * 16384, 2048L * 2048, 8L * 2048 * 2048, 8);
        softmax_kernel<<<32768, 256, 0, stream>>>(bufS);
        // Vt[e,t] = sum_d Wv[e,d]*xn[t,d] -> bufQ (Q dead)
        gemm_bt<u16, false><<<dim3(32, 128, 1), 256, 0, stream>>>(
            wv, xn, bufQ, 256, 256, 256, 4096, 0, 0, 0, 0, 0, 0, 1);
        // O[b,i,h*2048+d] = sum_j P[b,h,i,j]*Vt[h*2048+d, b*2048+j] -> bufK (K dead)
        gemm_bt<u16, false><<<dim3(16, 16, 16), 256, 0, stream>>>(
            bufS, bufQ, bufK, 2048, 2048, 4096, 16384,
            2048L * 2048, 8L * 2048 * 2048, 2048L * 4096, 2048, 2048, 2048L * 16384, 8);
        // out = O @ wo^T : K=16384 split 8x2048, fp32 atomic
        gemm_bt<float, true><<<dim3(2, 32, 8), 256, 0, stream>>>(
            bufK, wo, out, 2048, 16384, 16384, 256,
            2048, 0, 2048, 0, 0, 0, 8);
    } else if (ws_size >= BASE + 4 * MID) {
        // ---- Tier B: per-head loop (103 MiB) ----
        u16* Qb = (u16*)(buf);               // Q_h [b*2048+i, d], then O_h
        u16* Kb = (u16*)(buf + MID);         // K_h
        u16* Vt = (u16*)(buf + 2 * MID);     // Vt_h [d, b*2048+j]
        u16* Sb = (u16*)(buf + 3 * MID);     // S_h [b][i,j]
        for (int h = 0; h < 8; ++h) {
            const u16* wqh = wq + (size_t)h * 2048 * 256;
            const u16* wkh = wk + (size_t)h * 2048 * 256;
            const u16* wvh = wv + (size_t)h * 2048 * 256;
            gemm_bt<u16, false><<<dim3(16, 32, 1), 256, 0, stream>>>(
                xn, wqh, Qb, 256, 256, 256, 2048, 0, 0, 0, 0, 0, 0, 1);
            gemm_bt<u16, false><<<dim3(16, 32, 1), 256, 0, stream>>>(
                xn, wkh, Kb, 256, 256, 256, 2048, 0, 0, 0, 0, 0, 0, 1);
            gemm_bt<u16, false><<<dim3(32, 16, 1), 256, 0, stream>>>(
                wvh, xn, Vt, 256, 256, 256, 4096, 0, 0, 0, 0, 0, 0, 1);
            // S (z = batch): A=Qb+zb*2048*2048, B=Kb+..., C=Sb+...
            gemm_bt<u16, false><<<dim3(16, 16, 2), 256, 0, stream>>>(
                Qb, Kb, Sb, 2048, 2048, 2048, 2048,
                0, 2048L * 2048, 0, 2048L * 2048, 0, 2048L * 2048, 1);
            softmax_kernel<<<4096, 256, 0, stream>>>(Sb);
            // O (z = batch): B=Vt+zb*2048 (cols), C=Qb (reuse; Q dead)
            gemm_bt<u16, false><<<dim3(16, 16, 2), 256, 0, stream>>>(
                Sb, Vt, Qb, 2048, 2048, 4096, 2048,
                0, 2048L * 2048, 0, 2048, 0, 2048L * 2048, 1);
            // out += O_h @ wo_h^T : K=2048 split 4x512, atomic
            gemm_bt<float, true><<<dim3(2, 32, 4), 256, 0, stream>>>(
                Qb, wo + h * 2048, out, 512, 2048, 16384, 256,
                512, 0, 512, 0, 0, 0, 4);
        }
    } else {
        // ---- Tier C: per-(batch,head) loop (66 MiB) ----
        u16* Qb = (u16*)(buf);               // Q_bh [i,d], then O_bh
        u16* Kb = (u16*)(buf + SMALL);
        u16* Vt = (u16*)(buf + 2 * SMALL);
        u16* Sb = (u16*)(buf + 3 * SMALL);
        for (int b = 0; b < 2; ++b) {
            const u16* xnb = xn + (size_t)b * 2048 * 256;
            for (int h = 0; h < 8; ++h) {
                const u16* wqh = wq + (size_t)h * 2048 * 256;
                const u16* wkh = wk + (size_t)h * 2048 * 256;
                const u16* wvh = wv + (size_t)h * 2048 * 256;
                gemm_bt<u16, false><<<dim3(16, 16, 1), 256, 0, stream>>>(
                    xnb, wqh, Qb, 256, 256, 256, 2048, 0, 0, 0, 0, 0, 0, 1);
                gemm_bt<u16, false><<<dim3(16, 16, 1), 256, 0, stream>>>(
                    xnb, wkh, Kb, 256, 256, 256, 2048, 0, 0, 0, 0, 0, 0, 1);
                gemm_bt<u16, false><<<dim3(16, 16, 1), 256, 0, stream>>>(
                    wvh, xnb, Vt, 256, 256, 256, 2048, 0, 0, 0, 0, 0, 0, 1);
                gemm_bt<u16, false><<<dim3(16, 16, 1), 256, 0, stream>>>(
                    Qb, Kb, Sb, 2048, 2048, 2048, 2048, 0, 0, 0, 0, 0, 0, 1);
                softmax_kernel<<<2048, 256, 0, stream>>>(Sb);
                gemm_bt<u16, false><<<dim3(16, 16, 1), 256, 0, stream>>>(
                    Sb, Vt, Qb, 2048, 2048, 2048, 2048, 0, 0, 0, 0, 0, 0, 1);
                gemm_bt<float, true><<<dim3(2, 16, 4), 256, 0, stream>>>(
                    Qb, wo + h * 2048, out + (size_t)b * 2048 * 256, 512, 2048, 16384, 256,
                    512, 0, 512, 0, 0, 0, 4);
            }
        }
    }
}

// Round 3
// 1058.195 us; speedup vs baseline: 1.3537x; 1.3537x over previous
//
#include <hip/hip_runtime.h>

// Fused attention block (b=2, n=2048, dim=256, heads=8, inner=16384, d_head=2048)
// Grouped-head pipeline, g heads per dispatch (g = largest of {8,4,2,1} fitting ws):
//   cast W->bf16 (SCALE folded into Wq) ; LN->xn bf16 ;
//   per group: QK proj (fused, z=2) ; S = Q@K^T (z=2g) ; softmax ;
//              Vt = Wv@xn^T (into Q buf) ; O = P@Vt^T (into K buf, z=2g) ;
//              out += O@Wo^T (split-K 2g, fp32 atomic).
// All GEMMs B^T-form (both operands k-contiguous), m97 recipe: 128x128 tile,
// BK=32, mfma_f32_16x16x32_bf16, global_load_lds width=16, 2-barrier K-loop.
// 3 overlapped big buffers of g*16 MiB: BQ (Q->Vt), BK (K->O), BS (S->P).

typedef unsigned short u16;
typedef unsigned int u32;
typedef __bf16 bf16x8 __attribute__((ext_vector_type(8)));
typedef float f32x4 __attribute__((ext_vector_type(4)));

__device__ __forceinline__ u16 f2bf(float f) {
    u32 u = __builtin_bit_cast(u32, f);
    u += 0x7fffu + ((u >> 16) & 1u);   // RNE; inputs finite
    return (u16)(u >> 16);
}
__device__ __forceinline__ float bf2f(u16 h) {
    u32 u = ((u32)h) << 16;
    return __builtin_bit_cast(float, u);
}

#define GLDS16(G, L)                                                                  \
    __builtin_amdgcn_global_load_lds((const __attribute__((address_space(1))) u32*)(G), \
                                     (__attribute__((address_space(3))) u32*)(L), 16, 0, 0)

// ---------------------------------------------------------------------------
// B^T GEMM: C[m,n] (+)= sum_k A[m,k] * B[n,k].  M,N multiples of 128, K of 32.
// Batch/split-K via blockIdx.z: zh = z%H, zb = z/H; offsets via strides.
// 56 VGPR + 64 AGPR = 120 unified -> launch_bounds(256,4) keeps 4 blocks/CU.
// ---------------------------------------------------------------------------
template <typename OutT, bool ATOMIC>
__global__ void __launch_bounds__(256, 4) gemm_bt(
    const u16* __restrict__ A, const u16* __restrict__ B, OutT* __restrict__ C,
    int K, int lda, int ldb, int ldc,
    long sAh, long sAb, long sBh, long sBb, long sCh, long sCb, int H)
{
    __shared__ u16 ldsA[128 * 32];
    __shared__ u16 ldsB[128 * 32];

    const int z = blockIdx.z;
    const int zh = z % H, zb = z / H;
    A += (size_t)zh * sAh + (size_t)zb * sAb;
    B += (size_t)zh * sBh + (size_t)zb * sBb;
    C += (size_t)zh * sCh + (size_t)zb * sCb;

    const int bm = blockIdx.y * 128;
    const int bn = blockIdx.x * 128;
    const int t = threadIdx.x;
    const int w = t >> 6, l = t & 63;
    const int wm = w >> 1, wn = w & 1;          // 2x2 waves, each 64x64
    const int lr = l & 15, lk = l >> 4;         // frag row / k-chunk
    const int sw = lk ^ ((lr >> 1) & 3);        // XOR-swizzled slot (2-way LDS = free)

    // staging: 512 chunks of 16B per tile; thread t covers chunks t and 256+t.
    // LDS slot s of row m holds global k-chunk c = s ^ ((m>>1)&3).
    const int m0 = t >> 2, s0 = t & 3;
    const int c0 = s0 ^ ((m0 >> 1) & 3);
    const int m1 = 64 + m0;
    const int c1 = s0 ^ ((m1 >> 1) & 3);

    const u16* gA0 = A + (size_t)(bm + m0) * lda + c0 * 8;
    const u16* gA1 = A + (size_t)(bm + m1) * lda + c1 * 8;
    const u16* gB0 = B + (size_t)(bn + m0) * ldb + c0 * 8;
    const u16* gB1 = B + (size_t)(bn + m1) * ldb + c1 * 8;
    u16* lA0 = &ldsA[(t & ~63) * 8];            // wave-uniform base; HW adds lane*16B
    u16* lA1 = &ldsA[(256 + (t & ~63)) * 8];
    u16* lB0 = &ldsB[(t & ~63) * 8];
    u16* lB1 = &ldsB[(256 + (t & ~63)) * 8];

    f32x4 acc[4][4];
#pragma unroll
    for (int i = 0; i < 4; ++i)
#pragma unroll
        for (int j = 0; j < 4; ++j)
            acc[i][j] = f32x4{0.f, 0.f, 0.f, 0.f};

    const int nk = K >> 5;
    for (int kt = 0; kt < nk; ++kt) {
        __syncthreads();                         // protect LDS from prev iter's readers
        GLDS16(gA0, lA0); GLDS16(gA1, lA1);
        GLDS16(gB0, lB0); GLDS16(gB1, lB1);
        gA0 += 32; gA1 += 32; gB0 += 32; gB1 += 32;
        __syncthreads();                         // drains vmcnt -> tile staged

        bf16x8 av[4], bv[4];
#pragma unroll
        for (int i = 0; i < 4; ++i) {
            av[i] = *(const bf16x8*)&ldsA[(wm * 64 + i * 16 + lr) * 32 + sw * 8];
            bv[i] = *(const bf16x8*)&ldsB[(wn * 64 + i * 16 + lr) * 32 + sw * 8];
        }
#pragma unroll
        for (int i = 0; i < 4; ++i)
#pragma unroll
            for (int j = 0; j < 4; ++j)
                acc[i][j] = __builtin_amdgcn_mfma_f32_16x16x32_bf16(av[i], bv[j], acc[i][j], 0, 0, 0);
    }

    // C/D layout (m89-verified): col = lane&15, row = (lane>>4)*4 + reg
#pragma unroll
    for (int i = 0; i < 4; ++i) {
        const int row0 = bm + wm * 64 + i * 16 + lk * 4;
#pragma unroll
        for (int j = 0; j < 4; ++j) {
            const int col = bn + wn * 64 + j * 16 + lr;
#pragma unroll
            for (int r = 0; r < 4; ++r) {
                const size_t idx = (size_t)(row0 + r) * ldc + col;
                const float v = acc[i][j][r];
                if constexpr (ATOMIC) {
                    atomicAdd(&C[idx], v);
                } else if constexpr (sizeof(OutT) == 2) {
                    C[idx] = (OutT)f2bf(v);
                } else {
                    C[idx] = (OutT)v;
                }
            }
        }
    }
}

// ---------------------------------------------------------------------------
// LayerNorm over dim=256, out = xn*(gamma+1) in bf16. One wave per row.
// ---------------------------------------------------------------------------
__global__ void __launch_bounds__(64) ln_kernel(const float* __restrict__ x,
                                                const float* __restrict__ g,
                                                u16* __restrict__ xn)
{
    const size_t row = blockIdx.x;
    const int l = threadIdx.x;
    const float4 v = ((const float4*)(x + row * 256))[l];
    float s = v.x + v.y + v.z + v.w;
    float q = v.x * v.x + v.y * v.y + v.z * v.z + v.w * v.w;
#pragma unroll
    for (int o = 32; o > 0; o >>= 1) {
        s += __shfl_xor(s, o, 64);
        q += __shfl_xor(q, o, 64);
    }
    const float mu = s * (1.0f / 256.0f);
    const float var = q * (1.0f / 256.0f) - mu * mu;
    const float rs = rsqrtf(var + 1e-5f);
    const float4 gg = ((const float4*)g)[l];
    ushort4 o4;
    o4.x = f2bf((v.x - mu) * rs * (gg.x + 1.0f));
    o4.y = f2bf((v.y - mu) * rs * (gg.y + 1.0f));
    o4.z = f2bf((v.z - mu) * rs * (gg.z + 1.0f));
    o4.w = f2bf((v.w - mu) * rs * (gg.w + 1.0f));
    ((ushort4*)(xn + row * 256))[l] = o4;
}

// fp32 -> bf16 cast with scale (SCALE=0.125 folded into Wq; pow2 => exact)
__global__ void __launch_bounds__(256) cast_bf16_kernel(const float* __restrict__ src,
                                                        u16* __restrict__ dst, float scale)
{
    const size_t i = (size_t)blockIdx.x * 256 + threadIdx.x;
    const float4 v = ((const float4*)src)[i];
    ushort4 o4;
    o4.x = f2bf(v.x * scale);
    o4.y = f2bf(v.y * scale);
    o4.z = f2bf(v.z * scale);
    o4.w = f2bf(v.w * scale);
    ((ushort4*)dst)[i] = o4;
}

// row softmax over 2048 bf16 elements, in-place. 256 threads, 8 elems each.
__global__ void __launch_bounds__(256) softmax_kernel(u16* __restrict__ S)
{
    const size_t row = blockIdx.x;
    uint4* p = (uint4*)(S + row * 2048);
    const int t = threadIdx.x;
    const int wv = t >> 6, ln = t & 63;
    const uint4 d = p[t];
    u32 us[4] = {d.x, d.y, d.z, d.w};
    float x[8];
#pragma unroll
    for (int i = 0; i < 4; ++i) {
        x[2 * i]     = bf2f((u16)(us[i] & 0xffffu));
        x[2 * i + 1] = __builtin_bit_cast(float, us[i] & 0xffff0000u);
    }
    float m = x[0];
#pragma unroll
    for (int i = 1; i < 8; ++i) m = fmaxf(m, x[i]);
#pragma unroll
    for (int o = 32; o > 0; o >>= 1) m = fmaxf(m, __shfl_xor(m, o, 64));
    __shared__ float redm[4], reds[4];
    if (ln == 0) redm[wv] = m;
    __syncthreads();
    m = fmaxf(fmaxf(redm[0], redm[1]), fmaxf(redm[2], redm[3]));
    float e[8];
    float s = 0.f;
#pragma unroll
    for (int i = 0; i < 8; ++i) { e[i] = __expf(x[i] - m); s += e[i]; }
#pragma unroll
    for (int o = 32; o > 0; o >>= 1) s += __shfl_xor(s, o, 64);
    if (ln == 0) reds[wv] = s;
    __syncthreads();
    s = reds[0] + reds[1] + reds[2] + reds[3];
    const float inv = 1.0f / s;
    uint4 o4;
    o4.x = (u32)f2bf(e[0] * inv) | ((u32)f2bf(e[1] * inv) << 16);
    o4.y = (u32)f2bf(e[2] * inv) | ((u32)f2bf(e[3] * inv) << 16);
    o4.z = (u32)f2bf(e[4] * inv) | ((u32)f2bf(e[5] * inv) << 16);
    o4.w = (u32)f2bf(e[6] * inv) | ((u32)f2bf(e[7] * inv) << 16);
    p[t] = o4;
}

extern "C" void kernel_launch(void* const* d_in, const int* in_sizes, int n_in,
                              void* d_out, int out_size, void* d_ws, size_t ws_size,
                              hipStream_t stream)
{
    (void)in_sizes; (void)n_in;
    const float* x     = (const float*)d_in[0];
    const float* gamma = (const float*)d_in[1];
    const float* Wq    = (const float*)d_in[2];
    const float* Wk    = (const float*)d_in[3];
    const float* Wv    = (const float*)d_in[4];
    const float* Wo    = (const float*)d_in[5];
    float* out = (float*)d_out;

    char* ws = (char*)d_ws;
    const size_t WB   = 8388608;     // 16384*256*2  (one bf16 weight)
    const size_t XNB  = 2097152;     // 4096*256*2
    const size_t HB   = 16777216;    // per-head big buffer: 4096*2048*2
    const size_t BASE = 4 * WB + XNB;

    u16* wq = (u16*)(ws);
    u16* wk = (u16*)(ws + WB);      // wq->wk element stride = WB/2 = 4194304
    u16* wv = (u16*)(ws + 2 * WB);
    u16* wo = (u16*)(ws + 3 * WB);
    u16* xn = (u16*)(ws + 4 * WB);
    char* buf = ws + BASE;

    // pick largest head-group g with 3 overlapped buffers of g*HB fitting ws
    int g = 1;
    if (ws_size >= BASE + 3 * 8 * HB)      g = 8;
    else if (ws_size >= BASE + 3 * 4 * HB) g = 4;
    else if (ws_size >= BASE + 3 * 2 * HB) g = 2;

    const size_t gb = (size_t)g * HB;      // bytes per big buffer
    u16* BQ = (u16*)(buf);                 // Q_g, then Vt_g
    u16* BK = (u16*)(buf + gb);            // K_g, then O_g
    u16* BS = (u16*)(buf + 2 * gb);        // S_g -> P_g
    const long Ng = 2048L * g;             // group column width

    hipMemsetAsync(d_out, 0, (size_t)out_size * sizeof(float), stream);  // split-K accum

    cast_bf16_kernel<<<4096, 256, 0, stream>>>(Wq, wq, 0.125f);  // SCALE folded into Wq
    cast_bf16_kernel<<<4096, 256, 0, stream>>>(Wk, wk, 1.0f);
    cast_bf16_kernel<<<4096, 256, 0, stream>>>(Wv, wv, 1.0f);
    cast_bf16_kernel<<<4096, 256, 0, stream>>>(Wo, wo, 1.0f);

    ln_kernel<<<4096, 64, 0, stream>>>(x, gamma, xn);

    for (int gi = 0; gi < 8 / g; ++gi) {
        const u16* wq_g = wq + (size_t)gi * Ng * 256;   // (wk_g implied via sBh)
        const u16* wv_g = wv + (size_t)gi * Ng * 256;

        // Q_g | K_g = xn @ {wq_g,wk_g}^T : M=4096, N=Ng, K=256.  z: 0=Q, 1=K.
        gemm_bt<u16, false><<<dim3(16 * g, 32, 2), 256, 0, stream>>>(
            xn, wq_g, BQ, 256, 256, 256, (int)Ng,
            0, 0, 4194304L, 0, (long)g * 8388608L, 0, 2);

        // S[hh][b][i,j] = sum_d Q_g[b*2048+i, hh*2048+d] * K_g[b*2048+j, hh*2048+d]
        // z in [0,2g): zh=hh (H=g), zb=b.
        gemm_bt<u16, false><<<dim3(16, 16, 2 * g), 256, 0, stream>>>(
            BQ, BK, BS, 2048, (int)Ng, (int)Ng, 2048,
            2048L, 2048L * Ng, 2048L, 2048L * Ng,
            2048L * 2048 * 2, 2048L * 2048, g);

        softmax_kernel<<<4096 * g, 256, 0, stream>>>(BS);

        // Vt_g[e'=hh*2048+d, t=b*2048+j] = sum_d' wv_g[e',d']*xn[t,d'] -> BQ (Q dead)
        gemm_bt<u16, false><<<dim3(32, 16 * g, 1), 256, 0, stream>>>(
            wv_g, xn, BQ, 256, 256, 256, 4096, 0, 0, 0, 0, 0, 0, 1);

        // O_g[b*2048+i, hh*2048+d] = sum_j P[hh][b][i,j] * Vt_g[hh*2048+d, b*2048+j]
        // -> BK (K dead). z in [0,2g): zh=hh, zb=b.
        gemm_bt<u16, false><<<dim3(16, 16, 2 * g), 256, 0, stream>>>(
            BS, BQ, BK, 2048, 2048, 4096, (int)Ng,
            2048L * 2048 * 2, 2048L * 2048, 2048L * 4096, 2048L,
            2048L, 2048L * Ng, g);

        // out += O_g @ wo_g^T : M=4096, N=256, K=Ng split into 2g chunks of 1024.
        gemm_bt<float, true><<<dim3(2, 32, 2 * g), 256, 0, stream>>>(
            BK, wo + (size_t)gi * Ng, out, 1024, (int)Ng, 16384, 256,
            1024L, 0, 1024L, 0, 0, 0, 2 * g);
    }
}

// Round 4
// 814.560 us; speedup vs baseline: 1.7586x; 1.2991x over previous
//
#include <hip/hip_runtime.h>

// Fused attention block (b=2, n=2048, dim=256, heads=8, inner=16384, d_head=2048)
// Grouped-head pipeline, g heads per dispatch (g = largest of {8,4,2,1} fitting ws):
//   cast W->bf16 (SCALE folded into Wq) ; LN->xn bf16 ;
//   per group: QK proj (fused, z=2) ; S = Q@K^T (z=2g) ; softmax ;
//              V proj (into Q buf) ; Zt = Wo_h @ V_h^T (into K buf, z=2g) ;
//              out += P @ Zt (fp32 atomic over heads, z=2g).
// KEY ALGEBRA: out = (P·V^T)·Wo^T re-associated as P·(V·Wo_h^T): d_head(2048) >>
// d_model(256), so contracting V with Wo first cuts PV-side FLOPs 310->69 GF
// and removes the 134 MB O tensor entirely (total 687 -> 447 GF).
// All GEMMs B^T-form (both operands k-contiguous), m97 recipe: 128x128 tile,
// BK=32, mfma_f32_16x16x32_bf16, global_load_lds width=16, 2-barrier K-loop.
// 3 overlapped big buffers of g*16 MiB: BQ (Q->V), BK (K->Zt), BS (S->P).

typedef unsigned short u16;
typedef unsigned int u32;
typedef __bf16 bf16x8 __attribute__((ext_vector_type(8)));
typedef float f32x4 __attribute__((ext_vector_type(4)));

__device__ __forceinline__ u16 f2bf(float f) {
    u32 u = __builtin_bit_cast(u32, f);
    u += 0x7fffu + ((u >> 16) & 1u);   // RNE; inputs finite
    return (u16)(u >> 16);
}
__device__ __forceinline__ float bf2f(u16 h) {
    u32 u = ((u32)h) << 16;
    return __builtin_bit_cast(float, u);
}

#define GLDS16(G, L)                                                                  \
    __builtin_amdgcn_global_load_lds((const __attribute__((address_space(1))) u32*)(G), \
                                     (__attribute__((address_space(3))) u32*)(L), 16, 0, 0)

// ---------------------------------------------------------------------------
// B^T GEMM: C[m,n] (+)= sum_k A[m,k] * B[n,k].  M,N multiples of 128, K of 32.
// Batch/split-K via blockIdx.z: zh = z%H, zb = z/H; offsets via strides.
// ---------------------------------------------------------------------------
template <typename OutT, bool ATOMIC>
__global__ void __launch_bounds__(256, 4) gemm_bt(
    const u16* __restrict__ A, const u16* __restrict__ B, OutT* __restrict__ C,
    int K, int lda, int ldb, int ldc,
    long sAh, long sAb, long sBh, long sBb, long sCh, long sCb, int H)
{
    __shared__ u16 ldsA[128 * 32];
    __shared__ u16 ldsB[128 * 32];

    const int z = blockIdx.z;
    const int zh = z % H, zb = z / H;
    A += (size_t)zh * sAh + (size_t)zb * sAb;
    B += (size_t)zh * sBh + (size_t)zb * sBb;
    C += (size_t)zh * sCh + (size_t)zb * sCb;

    const int bm = blockIdx.y * 128;
    const int bn = blockIdx.x * 128;
    const int t = threadIdx.x;
    const int w = t >> 6, l = t & 63;
    const int wm = w >> 1, wn = w & 1;          // 2x2 waves, each 64x64
    const int lr = l & 15, lk = l >> 4;         // frag row / k-chunk
    const int sw = lk ^ ((lr >> 1) & 3);        // XOR-swizzled slot (2-way LDS = free)

    // staging: 512 chunks of 16B per tile; thread t covers chunks t and 256+t.
    // LDS slot s of row m holds global k-chunk c = s ^ ((m>>1)&3).
    const int m0 = t >> 2, s0 = t & 3;
    const int c0 = s0 ^ ((m0 >> 1) & 3);
    const int m1 = 64 + m0;
    const int c1 = s0 ^ ((m1 >> 1) & 3);

    const u16* gA0 = A + (size_t)(bm + m0) * lda + c0 * 8;
    const u16* gA1 = A + (size_t)(bm + m1) * lda + c1 * 8;
    const u16* gB0 = B + (size_t)(bn + m0) * ldb + c0 * 8;
    const u16* gB1 = B + (size_t)(bn + m1) * ldb + c1 * 8;
    u16* lA0 = &ldsA[(t & ~63) * 8];            // wave-uniform base; HW adds lane*16B
    u16* lA1 = &ldsA[(256 + (t & ~63)) * 8];
    u16* lB0 = &ldsB[(t & ~63) * 8];
    u16* lB1 = &ldsB[(256 + (t & ~63)) * 8];

    f32x4 acc[4][4];
#pragma unroll
    for (int i = 0; i < 4; ++i)
#pragma unroll
        for (int j = 0; j < 4; ++j)
            acc[i][j] = f32x4{0.f, 0.f, 0.f, 0.f};

    const int nk = K >> 5;
    for (int kt = 0; kt < nk; ++kt) {
        __syncthreads();                         // protect LDS from prev iter's readers
        GLDS16(gA0, lA0); GLDS16(gA1, lA1);
        GLDS16(gB0, lB0); GLDS16(gB1, lB1);
        gA0 += 32; gA1 += 32; gB0 += 32; gB1 += 32;
        __syncthreads();                         // drains vmcnt -> tile staged

        bf16x8 av[4], bv[4];
#pragma unroll
        for (int i = 0; i < 4; ++i) {
            av[i] = *(const bf16x8*)&ldsA[(wm * 64 + i * 16 + lr) * 32 + sw * 8];
            bv[i] = *(const bf16x8*)&ldsB[(wn * 64 + i * 16 + lr) * 32 + sw * 8];
        }
#pragma unroll
        for (int i = 0; i < 4; ++i)
#pragma unroll
            for (int j = 0; j < 4; ++j)
                acc[i][j] = __builtin_amdgcn_mfma_f32_16x16x32_bf16(av[i], bv[j], acc[i][j], 0, 0, 0);
    }

    // C/D layout (m89-verified): col = lane&15, row = (lane>>4)*4 + reg
#pragma unroll
    for (int i = 0; i < 4; ++i) {
        const int row0 = bm + wm * 64 + i * 16 + lk * 4;
#pragma unroll
        for (int j = 0; j < 4; ++j) {
            const int col = bn + wn * 64 + j * 16 + lr;
#pragma unroll
            for (int r = 0; r < 4; ++r) {
                const size_t idx = (size_t)(row0 + r) * ldc + col;
                const float v = acc[i][j][r];
                if constexpr (ATOMIC) {
                    atomicAdd(&C[idx], v);
                } else if constexpr (sizeof(OutT) == 2) {
                    C[idx] = (OutT)f2bf(v);
                } else {
                    C[idx] = (OutT)v;
                }
            }
        }
    }
}

// ---------------------------------------------------------------------------
// LayerNorm over dim=256, out = xn*(gamma+1) in bf16. One wave per row.
// ---------------------------------------------------------------------------
__global__ void __launch_bounds__(64) ln_kernel(const float* __restrict__ x,
                                                const float* __restrict__ g,
                                                u16* __restrict__ xn)
{
    const size_t row = blockIdx.x;
    const int l = threadIdx.x;
    const float4 v = ((const float4*)(x + row * 256))[l];
    float s = v.x + v.y + v.z + v.w;
    float q = v.x * v.x + v.y * v.y + v.z * v.z + v.w * v.w;
#pragma unroll
    for (int o = 32; o > 0; o >>= 1) {
        s += __shfl_xor(s, o, 64);
        q += __shfl_xor(q, o, 64);
    }
    const float mu = s * (1.0f / 256.0f);
    const float var = q * (1.0f / 256.0f) - mu * mu;
    const float rs = rsqrtf(var + 1e-5f);
    const float4 gg = ((const float4*)g)[l];
    ushort4 o4;
    o4.x = f2bf((v.x - mu) * rs * (gg.x + 1.0f));
    o4.y = f2bf((v.y - mu) * rs * (gg.y + 1.0f));
    o4.z = f2bf((v.z - mu) * rs * (gg.z + 1.0f));
    o4.w = f2bf((v.w - mu) * rs * (gg.w + 1.0f));
    ((ushort4*)(xn + row * 256))[l] = o4;
}

// fp32 -> bf16 cast with scale (SCALE=0.125 folded into Wq; pow2 => exact)
__global__ void __launch_bounds__(256) cast_bf16_kernel(const float* __restrict__ src,
                                                        u16* __restrict__ dst, float scale)
{
    const size_t i = (size_t)blockIdx.x * 256 + threadIdx.x;
    const float4 v = ((const float4*)src)[i];
    ushort4 o4;
    o4.x = f2bf(v.x * scale);
    o4.y = f2bf(v.y * scale);
    o4.z = f2bf(v.z * scale);
    o4.w = f2bf(v.w * scale);
    ((ushort4*)dst)[i] = o4;
}

// row softmax over 2048 bf16 elements, in-place. 256 threads, 8 elems each.
__global__ void __launch_bounds__(256) softmax_kernel(u16* __restrict__ S)
{
    const size_t row = blockIdx.x;
    uint4* p = (uint4*)(S + row * 2048);
    const int t = threadIdx.x;
    const int wv = t >> 6, ln = t & 63;
    const uint4 d = p[t];
    u32 us[4] = {d.x, d.y, d.z, d.w};
    float x[8];
#pragma unroll
    for (int i = 0; i < 4; ++i) {
        x[2 * i]     = bf2f((u16)(us[i] & 0xffffu));
        x[2 * i + 1] = __builtin_bit_cast(float, us[i] & 0xffff0000u);
    }
    float m = x[0];
#pragma unroll
    for (int i = 1; i < 8; ++i) m = fmaxf(m, x[i]);
#pragma unroll
    for (int o = 32; o > 0; o >>= 1) m = fmaxf(m, __shfl_xor(m, o, 64));
    __shared__ float redm[4], reds[4];
    if (ln == 0) redm[wv] = m;
    __syncthreads();
    m = fmaxf(fmaxf(redm[0], redm[1]), fmaxf(redm[2], redm[3]));
    float e[8];
    float s = 0.f;
#pragma unroll
    for (int i = 0; i < 8; ++i) { e[i] = __expf(x[i] - m); s += e[i]; }
#pragma unroll
    for (int o = 32; o > 0; o >>= 1) s += __shfl_xor(s, o, 64);
    if (ln == 0) reds[wv] = s;
    __syncthreads();
    s = reds[0] + reds[1] + reds[2] + reds[3];
    const float inv = 1.0f / s;
    uint4 o4;
    o4.x = (u32)f2bf(e[0] * inv) | ((u32)f2bf(e[1] * inv) << 16);
    o4.y = (u32)f2bf(e[2] * inv) | ((u32)f2bf(e[3] * inv) << 16);
    o4.z = (u32)f2bf(e[4] * inv) | ((u32)f2bf(e[5] * inv) << 16);
    o4.w = (u32)f2bf(e[6] * inv) | ((u32)f2bf(e[7] * inv) << 16);
    p[t] = o4;
}

extern "C" void kernel_launch(void* const* d_in, const int* in_sizes, int n_in,
                              void* d_out, int out_size, void* d_ws, size_t ws_size,
                              hipStream_t stream)
{
    (void)in_sizes; (void)n_in;
    const float* x     = (const float*)d_in[0];
    const float* gamma = (const float*)d_in[1];
    const float* Wq    = (const float*)d_in[2];
    const float* Wk    = (const float*)d_in[3];
    const float* Wv    = (const float*)d_in[4];
    const float* Wo    = (const float*)d_in[5];
    float* out = (float*)d_out;

    char* ws = (char*)d_ws;
    const size_t WB   = 8388608;     // 16384*256*2  (one bf16 weight)
    const size_t XNB  = 2097152;     // 4096*256*2
    const size_t HB   = 16777216;    // per-head big buffer: 4096*2048*2
    const size_t BASE = 4 * WB + XNB;

    u16* wq = (u16*)(ws);
    u16* wk = (u16*)(ws + WB);      // wq->wk element stride = WB/2 = 4194304
    u16* wv = (u16*)(ws + 2 * WB);
    u16* wo = (u16*)(ws + 3 * WB);
    u16* xn = (u16*)(ws + 4 * WB);
    char* buf = ws + BASE;

    // pick largest head-group g with 3 overlapped buffers of g*HB fitting ws
    int g = 1;
    if (ws_size >= BASE + 3 * 8 * HB)      g = 8;
    else if (ws_size >= BASE + 3 * 4 * HB) g = 4;
    else if (ws_size >= BASE + 3 * 2 * HB) g = 2;

    const size_t gb = (size_t)g * HB;      // bytes per big buffer
    u16* BQ = (u16*)(buf);                 // Q_g, then V_g
    u16* BK = (u16*)(buf + gb);            // K_g, then Zt_g
    u16* BS = (u16*)(buf + 2 * gb);        // S_g -> P_g
    const long Ng = 2048L * g;             // group column width

    hipMemsetAsync(d_out, 0, (size_t)out_size * sizeof(float), stream);  // atomic accum

    cast_bf16_kernel<<<4096, 256, 0, stream>>>(Wq, wq, 0.125f);  // SCALE folded into Wq
    cast_bf16_kernel<<<4096, 256, 0, stream>>>(Wk, wk, 1.0f);
    cast_bf16_kernel<<<4096, 256, 0, stream>>>(Wv, wv, 1.0f);
    cast_bf16_kernel<<<4096, 256, 0, stream>>>(Wo, wo, 1.0f);

    ln_kernel<<<4096, 64, 0, stream>>>(x, gamma, xn);

    for (int gi = 0; gi < 8 / g; ++gi) {
        const u16* wq_g = wq + (size_t)gi * Ng * 256;   // (wk_g implied via sBh)
        const u16* wv_g = wv + (size_t)gi * Ng * 256;
        const u16* wo_g = wo + (size_t)gi * Ng;         // column slice of Wo (256 x 16384)

        // Q_g | K_g = xn @ {wq_g,wk_g}^T : M=4096, N=Ng, K=256.  z: 0=Q, 1=K.
        gemm_bt<u16, false><<<dim3(16 * g, 32, 2), 256, 0, stream>>>(
            xn, wq_g, BQ, 256, 256, 256, (int)Ng,
            0, 0, 4194304L, 0, (long)g * 8388608L, 0, 2);

        // S[hh][b][i,j] = sum_d Q_g[b*2048+i, hh*2048+d] * K_g[b*2048+j, hh*2048+d]
        // z in [0,2g): zh=hh (H=g), zb=b.
        gemm_bt<u16, false><<<dim3(16, 16, 2 * g), 256, 0, stream>>>(
            BQ, BK, BS, 2048, (int)Ng, (int)Ng, 2048,
            2048L, 2048L * Ng, 2048L, 2048L * Ng,
            8388608L, 4194304L, g);

        softmax_kernel<<<4096 * g, 256, 0, stream>>>(BS);

        // V_g = xn @ wv_g^T : M=4096, N=Ng, K=256 -> BQ (Q dead after S)
        gemm_bt<u16, false><<<dim3(16 * g, 32, 1), 256, 0, stream>>>(
            xn, wv_g, BQ, 256, 256, 256, (int)Ng, 0, 0, 0, 0, 0, 0, 1);

        // Zt[hh][b][d', j] = sum_d wo_g[d', hh*2048+d] * V_g[b*2048+j, hh*2048+d]
        // M=256 (d'), N=2048 (j), K=2048 (d).  z: zh=hh, zb=b. -> BK (K dead)
        gemm_bt<u16, false><<<dim3(16, 2, 2 * g), 256, 0, stream>>>(
            wo_g, BQ, BK, 2048, 16384, (int)Ng, 2048,
            2048L, 0, 2048L, 2048L * Ng,
            1048576L, 524288L, g);

        // out[b*2048+i, d'] += sum_j P[hh][b][i,j] * Zt[hh][b][d', j]
        // M=2048, N=256, K=2048.  atomic over hh (and groups).
        gemm_bt<float, true><<<dim3(2, 16, 2 * g), 256, 0, stream>>>(
            BS, BK, out, 2048, 2048, 2048, 256,
            8388608L, 4194304L, 1048576L, 524288L,
            0L, 524288L, g);
    }
}

// Round 6
// 384.999 us; speedup vs baseline: 3.7207x; 2.1157x over previous
//
#include <hip/hip_runtime.h>

// Fused attention block (b=2, n=2048, dim=256, heads=8, inner=16384, d_head=2048)
// LOW-RANK FACTORIZATION: d_head(2048) >> d_model(256), so
//   S_h  = Q_h K_h^T = xn (Wq_h^T Wk_h) xn^T = xn M_h xn^T,  M_h: 256x256
//   Zt_h = Wo_h V_h^T = (Wo_h Wv_h) xn^T     = N_h xn^T,     N_h: 256x256
// Q,K,V,O never materialize. FLOPs 447 -> 77 GF.
// R5 bug: Y = M_h.xn^T gave S^T (M asymmetric) -> softmax on wrong axis.
// Fix: store Mt_h = M_h^T (swap A/B in the M GEMM) so S comes out untransposed.
// Pipeline: tcast Wq/Wk/Wv -> [h][a][d] bf16 (SCALE folded into Wq) ; cast Wo ;
//   LN -> xn ; Mt_h = wkt_h wqt_h^T ; N_h = wo_h wvt_h^T ; Y = xn Mt^T ;
//   Zt_b = N xn_b^T ; per chunk of gs heads: S = Y_h xn^T ; softmax ;
//   out += P Zt (fp32 atomic over heads).
// All GEMMs B^T-form (both operands k-contiguous), m97 recipe: 128x128 tile,
// BK=32, mfma_f32_16x16x32_bf16, global_load_lds width=16, 2-barrier K-loop.

typedef unsigned short u16;
typedef unsigned int u32;
typedef __bf16 bf16x8 __attribute__((ext_vector_type(8)));
typedef float f32x4 __attribute__((ext_vector_type(4)));

__device__ __forceinline__ u16 f2bf(float f) {
    u32 u = __builtin_bit_cast(u32, f);
    u += 0x7fffu + ((u >> 16) & 1u);   // RNE; inputs finite
    return (u16)(u >> 16);
}
__device__ __forceinline__ float bf2f(u16 h) {
    u32 u = ((u32)h) << 16;
    return __builtin_bit_cast(float, u);
}

#define GLDS16(G, L)                                                                  \
    __builtin_amdgcn_global_load_lds((const __attribute__((address_space(1))) u32*)(G), \
                                     (__attribute__((address_space(3))) u32*)(L), 16, 0, 0)

// ---------------------------------------------------------------------------
// B^T GEMM: C[m,n] (+)= sum_k A[m,k] * B[n,k].  M,N multiples of 128, K of 32.
// Batch/split-K via blockIdx.z: zh = z%H, zb = z/H; offsets via strides.
// ---------------------------------------------------------------------------
template <typename OutT, bool ATOMIC>
__global__ void __launch_bounds__(256, 4) gemm_bt(
    const u16* __restrict__ A, const u16* __restrict__ B, OutT* __restrict__ C,
    int K, int lda, int ldb, int ldc,
    long sAh, long sAb, long sBh, long sBb, long sCh, long sCb, int H)
{
    __shared__ u16 ldsA[128 * 32];
    __shared__ u16 ldsB[128 * 32];

    const int z = blockIdx.z;
    const int zh = z % H, zb = z / H;
    A += (size_t)zh * sAh + (size_t)zb * sAb;
    B += (size_t)zh * sBh + (size_t)zb * sBb;
    C += (size_t)zh * sCh + (size_t)zb * sCb;

    const int bm = blockIdx.y * 128;
    const int bn = blockIdx.x * 128;
    const int t = threadIdx.x;
    const int w = t >> 6, l = t & 63;
    const int wm = w >> 1, wn = w & 1;          // 2x2 waves, each 64x64
    const int lr = l & 15, lk = l >> 4;         // frag row / k-chunk
    const int sw = lk ^ ((lr >> 1) & 3);        // XOR-swizzled slot (2-way LDS = free)

    // staging: 512 chunks of 16B per tile; thread t covers chunks t and 256+t.
    // LDS slot s of row m holds global k-chunk c = s ^ ((m>>1)&3).
    const int m0 = t >> 2, s0 = t & 3;
    const int c0 = s0 ^ ((m0 >> 1) & 3);
    const int m1 = 64 + m0;
    const int c1 = s0 ^ ((m1 >> 1) & 3);

    const u16* gA0 = A + (size_t)(bm + m0) * lda + c0 * 8;
    const u16* gA1 = A + (size_t)(bm + m1) * lda + c1 * 8;
    const u16* gB0 = B + (size_t)(bn + m0) * ldb + c0 * 8;
    const u16* gB1 = B + (size_t)(bn + m1) * ldb + c1 * 8;
    u16* lA0 = &ldsA[(t & ~63) * 8];            // wave-uniform base; HW adds lane*16B
    u16* lA1 = &ldsA[(256 + (t & ~63)) * 8];
    u16* lB0 = &ldsB[(t & ~63) * 8];
    u16* lB1 = &ldsB[(256 + (t & ~63)) * 8];

    f32x4 acc[4][4];
#pragma unroll
    for (int i = 0; i < 4; ++i)
#pragma unroll
        for (int j = 0; j < 4; ++j)
            acc[i][j] = f32x4{0.f, 0.f, 0.f, 0.f};

    const int nk = K >> 5;
    for (int kt = 0; kt < nk; ++kt) {
        __syncthreads();                         // protect LDS from prev iter's readers
        GLDS16(gA0, lA0); GLDS16(gA1, lA1);
        GLDS16(gB0, lB0); GLDS16(gB1, lB1);
        gA0 += 32; gA1 += 32; gB0 += 32; gB1 += 32;
        __syncthreads();                         // drains vmcnt -> tile staged

        bf16x8 av[4], bv[4];
#pragma unroll
        for (int i = 0; i < 4; ++i) {
            av[i] = *(const bf16x8*)&ldsA[(wm * 64 + i * 16 + lr) * 32 + sw * 8];
            bv[i] = *(const bf16x8*)&ldsB[(wn * 64 + i * 16 + lr) * 32 + sw * 8];
        }
#pragma unroll
        for (int i = 0; i < 4; ++i)
#pragma unroll
            for (int j = 0; j < 4; ++j)
                acc[i][j] = __builtin_amdgcn_mfma_f32_16x16x32_bf16(av[i], bv[j], acc[i][j], 0, 0, 0);
    }

    // C/D layout (m89-verified): col = lane&15, row = (lane>>4)*4 + reg
#pragma unroll
    for (int i = 0; i < 4; ++i) {
        const int row0 = bm + wm * 64 + i * 16 + lk * 4;
#pragma unroll
        for (int j = 0; j < 4; ++j) {
            const int col = bn + wn * 64 + j * 16 + lr;
#pragma unroll
            for (int r = 0; r < 4; ++r) {
                const size_t idx = (size_t)(row0 + r) * ldc + col;
                const float v = acc[i][j][r];
                if constexpr (ATOMIC) {
                    atomicAdd(&C[idx], v);
                } else if constexpr (sizeof(OutT) == 2) {
                    C[idx] = (OutT)f2bf(v);
                } else {
                    C[idx] = (OutT)v;
                }
            }
        }
    }
}

// ---------------------------------------------------------------------------
// Transposed cast: src fp32 [8][2048][256] -> dst bf16 [8][256][2048],
// dst[h][a][d] = src[h][d][a]*scale.  64x64 tiles via LDS (66-pad: 2-way = free).
// ---------------------------------------------------------------------------
__global__ void __launch_bounds__(256) tcast_kernel(const float* __restrict__ src,
                                                    u16* __restrict__ dst, float scale)
{
    __shared__ u16 tile[64][66];
    const int h = blockIdx.z;
    const int d0 = blockIdx.x * 64;
    const int a0 = blockIdx.y * 64;
    const int t = threadIdx.x;
    const int c = t & 63, r0 = t >> 6;
#pragma unroll
    for (int rr = 0; rr < 16; ++rr) {
        const int r = r0 + rr * 4;
        tile[r][c] = f2bf(src[((size_t)h * 2048 + d0 + r) * 256 + a0 + c] * scale);
    }
    __syncthreads();
#pragma unroll
    for (int rr = 0; rr < 16; ++rr) {
        const int r = r0 + rr * 4;
        dst[((size_t)h * 256 + a0 + r) * 2048 + d0 + c] = tile[c][r];
    }
}

// ---------------------------------------------------------------------------
// LayerNorm over dim=256, out = xn*(gamma+1) in bf16. One wave per row.
// ---------------------------------------------------------------------------
__global__ void __launch_bounds__(64) ln_kernel(const float* __restrict__ x,
                                                const float* __restrict__ g,
                                                u16* __restrict__ xn)
{
    const size_t row = blockIdx.x;
    const int l = threadIdx.x;
    const float4 v = ((const float4*)(x + row * 256))[l];
    float s = v.x + v.y + v.z + v.w;
    float q = v.x * v.x + v.y * v.y + v.z * v.z + v.w * v.w;
#pragma unroll
    for (int o = 32; o > 0; o >>= 1) {
        s += __shfl_xor(s, o, 64);
        q += __shfl_xor(q, o, 64);
    }
    const float mu = s * (1.0f / 256.0f);
    const float var = q * (1.0f / 256.0f) - mu * mu;
    const float rs = rsqrtf(var + 1e-5f);
    const float4 gg = ((const float4*)g)[l];
    ushort4 o4;
    o4.x = f2bf((v.x - mu) * rs * (gg.x + 1.0f));
    o4.y = f2bf((v.y - mu) * rs * (gg.y + 1.0f));
    o4.z = f2bf((v.z - mu) * rs * (gg.z + 1.0f));
    o4.w = f2bf((v.w - mu) * rs * (gg.w + 1.0f));
    ((ushort4*)(xn + row * 256))[l] = o4;
}

// fp32 -> bf16 cast (plain)
__global__ void __launch_bounds__(256) cast_bf16_kernel(const float* __restrict__ src,
                                                        u16* __restrict__ dst, float scale)
{
    const size_t i = (size_t)blockIdx.x * 256 + threadIdx.x;
    const float4 v = ((const float4*)src)[i];
    ushort4 o4;
    o4.x = f2bf(v.x * scale);
    o4.y = f2bf(v.y * scale);
    o4.z = f2bf(v.z * scale);
    o4.w = f2bf(v.w * scale);
    ((ushort4*)dst)[i] = o4;
}

// row softmax over 2048 bf16 elements, in-place. 256 threads, 8 elems each.
__global__ void __launch_bounds__(256) softmax_kernel(u16* __restrict__ S)
{
    const size_t row = blockIdx.x;
    uint4* p = (uint4*)(S + row * 2048);
    const int t = threadIdx.x;
    const int wv = t >> 6, ln = t & 63;
    const uint4 d = p[t];
    u32 us[4] = {d.x, d.y, d.z, d.w};
    float x[8];
#pragma unroll
    for (int i = 0; i < 4; ++i) {
        x[2 * i]     = bf2f((u16)(us[i] & 0xffffu));
        x[2 * i + 1] = __builtin_bit_cast(float, us[i] & 0xffff0000u);
    }
    float m = x[0];
#pragma unroll
    for (int i = 1; i < 8; ++i) m = fmaxf(m, x[i]);
#pragma unroll
    for (int o = 32; o > 0; o >>= 1) m = fmaxf(m, __shfl_xor(m, o, 64));
    __shared__ float redm[4], reds[4];
    if (ln == 0) redm[wv] = m;
    __syncthreads();
    m = fmaxf(fmaxf(redm[0], redm[1]), fmaxf(redm[2], redm[3]));
    float e[8];
    float s = 0.f;
#pragma unroll
    for (int i = 0; i < 8; ++i) { e[i] = __expf(x[i] - m); s += e[i]; }
#pragma unroll
    for (int o = 32; o > 0; o >>= 1) s += __shfl_xor(s, o, 64);
    if (ln == 0) reds[wv] = s;
    __syncthreads();
    s = reds[0] + reds[1] + reds[2] + reds[3];
    const float inv = 1.0f / s;
    uint4 o4;
    o4.x = (u32)f2bf(e[0] * inv) | ((u32)f2bf(e[1] * inv) << 16);
    o4.y = (u32)f2bf(e[2] * inv) | ((u32)f2bf(e[3] * inv) << 16);
    o4.z = (u32)f2bf(e[4] * inv) | ((u32)f2bf(e[5] * inv) << 16);
    o4.w = (u32)f2bf(e[6] * inv) | ((u32)f2bf(e[7] * inv) << 16);
    p[t] = o4;
}

extern "C" void kernel_launch(void* const* d_in, const int* in_sizes, int n_in,
                              void* d_out, int out_size, void* d_ws, size_t ws_size,
                              hipStream_t stream)
{
    (void)in_sizes; (void)n_in;
    const float* x     = (const float*)d_in[0];
    const float* gamma = (const float*)d_in[1];
    const float* Wq    = (const float*)d_in[2];
    const float* Wk    = (const float*)d_in[3];
    const float* Wv    = (const float*)d_in[4];
    const float* Wo    = (const float*)d_in[5];
    float* out = (float*)d_out;

    char* ws = (char*)d_ws;
    const size_t MB = 1048576;
    u16* wqt = (u16*)(ws);             // [8][256][2048] bf16, 8 MB (SCALE folded)
    u16* wkt = (u16*)(ws + 8 * MB);    // 8 MB
    u16* wvt = (u16*)(ws + 16 * MB);   // 8 MB
    u16* wo  = (u16*)(ws + 24 * MB);   // [256][16384] bf16, 8 MB
    u16* xn  = (u16*)(ws + 32 * MB);   // [4096][256] bf16, 2 MB
    u16* Mt  = (u16*)(ws + 34 * MB);   // [8*256][256] bf16: Mt_h = (Wq_h^T Wk_h)^T
    u16* Nb  = (u16*)(ws + 35 * MB);   // [8*256][256] bf16, 1 MB
    u16* Y   = (u16*)(ws + 36 * MB);   // [4096][2048] bf16, 16 MB
    u16* Zt  = (u16*)(ws + 52 * MB);   // [2][2048][2048] bf16, 16 MB
    u16* S   = (u16*)(ws + 68 * MB);   // [gs][2][2048][2048] bf16, gs*16 MB
    const size_t BASE2 = 68 * MB;

    // largest head-chunk gs in {8,4,2,1} whose S buffer fits
    int gs = 1;
    if (ws_size >= BASE2 + 8 * 16 * MB)      gs = 8;
    else if (ws_size >= BASE2 + 4 * 16 * MB) gs = 4;
    else if (ws_size >= BASE2 + 2 * 16 * MB) gs = 2;

    hipMemsetAsync(d_out, 0, (size_t)out_size * sizeof(float), stream);  // atomic accum

    tcast_kernel<<<dim3(32, 4, 8), 256, 0, stream>>>(Wq, wqt, 0.125f);  // SCALE folded
    tcast_kernel<<<dim3(32, 4, 8), 256, 0, stream>>>(Wk, wkt, 1.0f);
    tcast_kernel<<<dim3(32, 4, 8), 256, 0, stream>>>(Wv, wvt, 1.0f);
    cast_bf16_kernel<<<4096, 256, 0, stream>>>(Wo, wo, 1.0f);
    ln_kernel<<<4096, 64, 0, stream>>>(x, gamma, xn);

    // Mt_h[a,c] = sum_e wkt_h[a,e] * wqt_h[c,e] = M_h[c,a] : 256x256, K=2048, z=head
    // (A/B swapped vs R5 -- this is the S-transpose fix)
    gemm_bt<u16, false><<<dim3(2, 2, 8), 256, 0, stream>>>(
        wkt, wqt, Mt, 2048, 2048, 2048, 256,
        524288L, 0, 524288L, 0, 65536L, 0, 8);

    // N_h[d',a] = sum_e Wo[d', h*2048+e] * wvt_h[a,e] : 256x256, K=2048, z=head
    gemm_bt<u16, false><<<dim3(2, 2, 8), 256, 0, stream>>>(
        wo, wvt, Nb, 2048, 16384, 2048, 256,
        2048L, 0, 524288L, 0, 65536L, 0, 8);

    // Y[t, h*256+a] = sum_c xn[t,c] * Mt[h*256+a, c] = sum_c xn[t,c] M_h[c,a]
    gemm_bt<u16, false><<<dim3(16, 32, 1), 256, 0, stream>>>(
        xn, Mt, Y, 256, 256, 256, 2048, 0, 0, 0, 0, 0, 0, 1);

    // Zt[b][h*256+d', j] = sum_a N[h*256+d', a] * xn[b*2048+j, a] : K=256, z=b
    gemm_bt<u16, false><<<dim3(16, 16, 2), 256, 0, stream>>>(
        Nb, xn, Zt, 256, 256, 256, 2048,
        0, 0, 0, 524288L, 0, 4194304L, 1);

    for (int ci = 0; ci < 8 / gs; ++ci) {
        // S[hh][b][i,j] = sum_a Y[b*2048+i, (ci*gs+hh)*256+a] * xn[b*2048+j, a]
        //              = sum_{a,c} xn[i,a] M_h[a,c] xn[j,c]  (untransposed now)
        // K=256, z in [0,2*gs): zh=hh, zb=b
        gemm_bt<u16, false><<<dim3(16, 16, 2 * gs), 256, 0, stream>>>(
            Y + (size_t)ci * gs * 256, xn, S, 256, 2048, 256, 2048,
            256L, 4194304L, 0, 524288L, 8388608L, 4194304L, gs);

        softmax_kernel<<<4096 * gs, 256, 0, stream>>>(S);

        // out[b*2048+i, d'] += sum_j P[hh][b][i,j] * Zt[b][(ci*gs+hh)*256+d', j]
        // K=2048, atomic over heads. z: zh=hh, zb=b
        gemm_bt<float, true><<<dim3(2, 16, 2 * gs), 256, 0, stream>>>(
            S, Zt + (size_t)ci * gs * 524288, out, 2048, 2048, 2048, 256,
            8388608L, 4194304L, 524288L, 4194304L, 0L, 524288L, gs);
    }
}